// Round 7
// baseline (138.802 us; speedup 1.0000x reference)
//
#include <hip/hip_runtime.h>
#include <hip/hip_bf16.h>
#include <math.h>

#define NB 16
#define NT 2048
#define ND 512
#define NH 64
#define NW 16   // waves per block

typedef __attribute__((ext_vector_type(8))) short short8;
typedef __attribute__((ext_vector_type(4))) float float4v;

// ---------------------------------------------------------------------------
// mask dtype robustness: byte layout -> first int32 reads 0x01010101 (lengths
// >= T/2 so mask[0..3] all true); int32 layout -> 1; f32 layout -> 0x3F800000.
// ---------------------------------------------------------------------------
__device__ __forceinline__ bool mask_is_bytes(const int* m) {
    return m[0] == 0x01010101;
}
__device__ __forceinline__ bool mask_at(const int* m, bool bytes, int i) {
    if (bytes) return ((const unsigned char*)m)[i] != 0;
    return m[i] != 0;
}

// Minkowski dot, metric folded into `a`; explicit fmaf so pass 1 / pass 2
// recompute bitwise-identical values.
__device__ __forceinline__ float dot4(float4 a, float4 p) {
    float d = a.x * p.x;
    d = __builtin_fmaf(a.y, p.y, d);
    d = __builtin_fmaf(a.z, p.z, d);
    d = __builtin_fmaf(a.w, p.w, d);
    return d;
}

__device__ __forceinline__ unsigned short f2bf(float x) {
    unsigned int u = __float_as_uint(x);
    u += 0x7fffu + ((u >> 16) & 1u);
    return (unsigned short)(u >> 16);
}

// sorted-desc top-8 insert chain (1 fmax + 7 med3)
#define CHAIN8(v0,v1,v2,v3,v4,v5,v6,v7,d) do {                 \
    float n0 = fmaxf(v0, d);                                    \
    float n1 = __builtin_amdgcn_fmed3f(d, v0, v1);              \
    float n2 = __builtin_amdgcn_fmed3f(d, v1, v2);              \
    float n3 = __builtin_amdgcn_fmed3f(d, v2, v3);              \
    float n4 = __builtin_amdgcn_fmed3f(d, v3, v4);              \
    float n5 = __builtin_amdgcn_fmed3f(d, v4, v5);              \
    float n6 = __builtin_amdgcn_fmed3f(d, v5, v6);              \
    float n7 = __builtin_amdgcn_fmed3f(d, v6, v7);              \
    v0 = n0; v1 = n1; v2 = n2; v3 = n3;                         \
    v4 = n4; v5 = n5; v6 = n6; v7 = n7;                         \
} while (0)

// ---------------------------------------------------------------------------
// Kernel A (prep): blocks [0,128) transpose W2 fp32[k][n] -> bf16 W2t[n][k];
// blocks [128,256) compute P (E,px,py,pz) per token once per batch into Pg.
// Masked tokens get sentinel (-1e30,0,0,0).
// ---------------------------------------------------------------------------
__global__ void __launch_bounds__(256) prep_kernel(
        const float* __restrict__ tok, const int* __restrict__ mask,
        const float* __restrict__ W2, unsigned short* __restrict__ W2t,
        float4* __restrict__ Pg) {
    int i = blockIdx.x * 256 + threadIdx.x;
    if (i < ND * NH) {
        int n = i & (ND - 1), k = i >> 9;
        W2t[n * NH + k] = f2bf(W2[k * ND + n]);
    } else {
        int j = i - ND * NH;                    // 0 .. NB*NT-1
        const bool mb = mask_is_bytes(mask);
        float4 tv = ((const float4*)tok)[j];
        bool m = mask_at(mask, mb, j);
        float E = tv.x, Pt = tv.y, eta = tv.z, phi = tv.w;
        float px = Pt * cosf(phi);
        float py = Pt * sinf(phi);
        float pz = Pt * sinhf(fminf(fmaxf(eta, -20.f), 20.f));
        Pg[j] = m ? make_float4(E, px, py, pz)
                  : make_float4(-1e30f, 0.f, 0.f, 0.f);
    }
}

// ---------------------------------------------------------------------------
// Kernel B (R7): R6 16-wave structure with the spill killed.
//  - __launch_bounds__(1024, 4): 4 waves/EU floor -> VGPR cap 128 (R6's
//    implicit 64-cap spilled pass-2 accumulators -> +21 MB scratch writes).
//  - pass 2 wave-split: waves 0-7 handle tile-A queries, 8-15 tile-B,
//    each scanning chunk L/8; live accumulators 24 -> 12.
// Phases: stage+count | pass1 (both tiles per read, chunk L/16) | waves 0/1
// merge -> thresholds in LDS | pass2 (wave-split, chunk L/8) | waves 0/1
// reduce -> mass | parallel epilogue (waves 0-7 tile A, 8-15 tile B).
// LDS (floats): [0,8192) Plds (-> hsA/hsB/mass after B4)
//               VTA [8192,16384)  VTB [16384,24576)
//               PSA [8192,14336)  PSB [14336,20480)  (alias dead VT)
// 128 KB + thS/wcnt -> 1 block/CU, 16 waves resident.
// ---------------------------------------------------------------------------
#define VTA(w2, j, l)  S[ 8192 + ((w2) * 8 + (j)) * 64 + (l)]
#define VTB(w2, j, l)  S[16384 + ((w2) * 8 + (j)) * 64 + (l)]
#define PSA(w2, c, l)  S[ 8192 + ((w2) * 12 + (c)) * 64 + (l)]
#define PSB(w2, c, l)  S[14336 + ((w2) * 12 + (c)) * 64 + (l)]

__global__ void __launch_bounds__(1024, 4) fused_topk_mass_mlp_kernel(
        const int* __restrict__ mask,
        const float* __restrict__ W1,
        const float* __restrict__ b1,
        const unsigned short* __restrict__ W2t,
        const float* __restrict__ b2,
        const float4* __restrict__ Pg,
        float* __restrict__ out) {
    __shared__ __align__(16) float S[32768];   // 128 KB
    __shared__ float thS[6][64];               // thA2/4/8, thB2/4/8
    __shared__ int wcnt[NW];

    float* Plds = S;
    unsigned short (*hsA)[88] = (unsigned short(*)[88])S;            // 2816 fl
    unsigned short (*hsB)[88] = (unsigned short(*)[88])(S + 2816);   // 2816 fl
    float (*mass_s)[128]      = (float(*)[128])(S + 5632);           // 384 fl

    const int b    = blockIdx.y;
    const int x    = blockIdx.x;           // 0..15
    const int tA   = 64 * x;               // tokens 0..1023 (always < L)
    const int tB   = 1024 + 64 * x;        // tokens 1024..2047
    const int tid  = threadIdx.x;
    const int lane = tid & 63;
    const int w    = tid >> 6;             // 0..15
    const bool mb  = mask_is_bytes(mask);
    const float NEGBIG = -3.402823466e38f;
    const float MZ = sqrtf(1e-8f);

    // ---- stage Pg -> Plds; count L via ballots ----
    int cnt = 0;
    const float4* __restrict__ Pb = Pg + (size_t)b * NT;
#pragma unroll
    for (int it = 0; it < 2; ++it) {
        int i = tid + it * 1024;
        *(float4*)&Plds[i * 4] = Pb[i];
        cnt += (int)__popcll(__ballot(mask_at(mask, mb, b * NT + i)));
    }
    if (lane == 0) wcnt[w] = cnt;
    __syncthreads();                               // B1

    int L = 0;
#pragma unroll
    for (int j = 0; j < NW; ++j) L += wcnt[j];
    const int C    = (L + NW - 1) / NW;            // pass-1 chunk (16 waves)
    const int sBeg = w * C;
    const int sEnd = min(sBeg + C, L);
    const bool hasB = tB < L;                      // block-uniform

    float4 pA  = *(const float4*)&Plds[(tA + lane) * 4];
    float4 pBq = *(const float4*)&Plds[(tB + lane) * 4];
    float4 aA = make_float4(pA.x, -pA.y, -pA.z, -pA.w);
    float4 aB = make_float4(pBq.x, -pBq.y, -pBq.z, -pBq.w);

    float vA0 = NEGBIG, vA1 = NEGBIG, vA2 = NEGBIG, vA3 = NEGBIG;
    float vA4 = NEGBIG, vA5 = NEGBIG, vA6 = NEGBIG, vA7 = NEGBIG;
    float vB0 = NEGBIG, vB1 = NEGBIG, vB2 = NEGBIG, vB3 = NEGBIG;
    float vB4 = NEGBIG, vB5 = NEGBIG, vB6 = NEGBIG, vB7 = NEGBIG;

    // ---- pass 1: chunk-local top-8 for both query tiles per read ----
    if (hasB) {
#pragma unroll 4
        for (int s = sBeg; s < sEnd; ++s) {
            float4 ps = *(const float4*)&Plds[s * 4];
            float dA = dot4(aA, ps);
            float dB = dot4(aB, ps);
            CHAIN8(vA0, vA1, vA2, vA3, vA4, vA5, vA6, vA7, dA);
            CHAIN8(vB0, vB1, vB2, vB3, vB4, vB5, vB6, vB7, dB);
        }
    } else {
#pragma unroll 4
        for (int s = sBeg; s < sEnd; ++s) {
            float4 ps = *(const float4*)&Plds[s * 4];
            float dA = dot4(aA, ps);
            CHAIN8(vA0, vA1, vA2, vA3, vA4, vA5, vA6, vA7, dA);
        }
    }
    VTA(w, 0, lane) = vA0; VTA(w, 1, lane) = vA1;
    VTA(w, 2, lane) = vA2; VTA(w, 3, lane) = vA3;
    VTA(w, 4, lane) = vA4; VTA(w, 5, lane) = vA5;
    VTA(w, 6, lane) = vA6; VTA(w, 7, lane) = vA7;
    if (hasB) {
        VTB(w, 0, lane) = vB0; VTB(w, 1, lane) = vB1;
        VTB(w, 2, lane) = vB2; VTB(w, 3, lane) = vB3;
        VTB(w, 4, lane) = vB4; VTB(w, 5, lane) = vB5;
        VTB(w, 6, lane) = vB6; VTB(w, 7, lane) = vB7;
    }
    __syncthreads();                               // B2

    // ---- dedicated merge: wave 0 merges A, wave 1 merges B ----
    if (w == 0) {
        float m0 = NEGBIG, m1 = NEGBIG, m2_ = NEGBIG, m3 = NEGBIG;
        float m4 = NEGBIG, m5 = NEGBIG, m6 = NEGBIG, m7 = NEGBIG;
#pragma unroll
        for (int w2 = 0; w2 < NW; ++w2)
#pragma unroll
            for (int j = 0; j < 8; ++j) {
                float d = VTA(w2, j, lane);
                CHAIN8(m0, m1, m2_, m3, m4, m5, m6, m7, d);
            }
        thS[0][lane] = m1; thS[1][lane] = m3; thS[2][lane] = m7;
    } else if (w == 1 && hasB) {
        float m0 = NEGBIG, m1 = NEGBIG, m2_ = NEGBIG, m3 = NEGBIG;
        float m4 = NEGBIG, m5 = NEGBIG, m6 = NEGBIG, m7 = NEGBIG;
#pragma unroll
        for (int w2 = 0; w2 < NW; ++w2)
#pragma unroll
            for (int j = 0; j < 8; ++j) {
                float d = VTB(w2, j, lane);
                CHAIN8(m0, m1, m2_, m3, m4, m5, m6, m7, d);
            }
        thS[3][lane] = m1; thS[4][lane] = m3; thS[5][lane] = m7;
    }
    __syncthreads();                               // B3 (VT dead)

    // ---- pass 2: wave-split exact-membership partial sums ----
    // waves 0-7: tile A queries; waves 8-15: tile B queries. chunk L/8.
    {
        const bool isB  = (w >= 8);
        const int  wl8  = w & 7;
        const int  C2   = (L + 7) >> 3;
        const int  pBeg = wl8 * C2;
        const int  pEnd = min(pBeg + C2, L);
        const bool act  = !isB || hasB;

        float s2x = 0.f, s2y = 0.f, s2z = 0.f, s2w = 0.f;
        float s4x = 0.f, s4y = 0.f, s4z = 0.f, s4w = 0.f;
        float s8x = 0.f, s8y = 0.f, s8z = 0.f, s8w = 0.f;

        if (act) {
            const float4 aQ = isB ? aB : aA;
            const float th2v = isB ? thS[3][lane] : thS[0][lane];
            const float th4v = isB ? thS[4][lane] : thS[1][lane];
            const float th8v = isB ? thS[5][lane] : thS[2][lane];
#pragma unroll 4
            for (int s = pBeg; s < pEnd; ++s) {
                float4 ps = *(const float4*)&Plds[s * 4];
                float d = dot4(aQ, ps);
                if (d >= th8v) {
                    s8x += ps.x; s8y += ps.y; s8z += ps.z; s8w += ps.w;
                    if (d >= th4v) {
                        s4x += ps.x; s4y += ps.y; s4z += ps.z; s4w += ps.w;
                        if (d >= th2v) {
                            s2x += ps.x; s2y += ps.y; s2z += ps.z; s2w += ps.w;
                        }
                    }
                }
            }
        }
        if (!isB) {
            PSA(wl8, 0, lane) = s2x;  PSA(wl8, 1, lane) = s2y;
            PSA(wl8, 2, lane) = s2z;  PSA(wl8, 3, lane) = s2w;
            PSA(wl8, 4, lane) = s4x;  PSA(wl8, 5, lane) = s4y;
            PSA(wl8, 6, lane) = s4z;  PSA(wl8, 7, lane) = s4w;
            PSA(wl8, 8, lane) = s8x;  PSA(wl8, 9, lane) = s8y;
            PSA(wl8, 10, lane) = s8z; PSA(wl8, 11, lane) = s8w;
        } else if (hasB) {
            PSB(wl8, 0, lane) = s2x;  PSB(wl8, 1, lane) = s2y;
            PSB(wl8, 2, lane) = s2z;  PSB(wl8, 3, lane) = s2w;
            PSB(wl8, 4, lane) = s4x;  PSB(wl8, 5, lane) = s4y;
            PSB(wl8, 6, lane) = s4z;  PSB(wl8, 7, lane) = s4w;
            PSB(wl8, 8, lane) = s8x;  PSB(wl8, 9, lane) = s8y;
            PSB(wl8, 10, lane) = s8z; PSB(wl8, 11, lane) = s8w;
        }
    }
    __syncthreads();                               // B4 (Plds dead)

    // ---- waves 0/1: reduce + masses (mass_s aliases old Plds space) ----
    {
        auto massf = [](float sx, float sy, float sz, float sw) -> float {
            float q = sx * sx;
            q = __builtin_fmaf(-sy, sy, q);
            q = __builtin_fmaf(-sz, sz, q);
            q = __builtin_fmaf(-sw, sw, q);
            q = fmaxf(q, 0.f);
            return sqrtf(q + 1e-8f);
        };
        if (w == 0) {
            float tot[12];
#pragma unroll
            for (int c = 0; c < 12; ++c) {
                float acc = 0.f;
#pragma unroll
                for (int w2 = 0; w2 < 8; ++w2) acc += PSA(w2, c, lane);
                tot[c] = acc;
            }
            // tileA tokens (< 1024 <= L) are always valid
            mass_s[0][lane] = massf(tot[0], tot[1], tot[2], tot[3]);
            mass_s[1][lane] = massf(tot[4], tot[5], tot[6], tot[7]);
            mass_s[2][lane] = massf(tot[8], tot[9], tot[10], tot[11]);
        } else if (w == 1) {
            if (hasB) {
                float tot[12];
#pragma unroll
                for (int c = 0; c < 12; ++c) {
                    float acc = 0.f;
#pragma unroll
                    for (int w2 = 0; w2 < 8; ++w2) acc += PSB(w2, c, lane);
                    tot[c] = acc;
                }
                const bool maskt = (tB + lane) < L;   // mask monotone
                mass_s[0][64 + lane] = maskt ? massf(tot[0], tot[1], tot[2], tot[3]) : MZ;
                mass_s[1][64 + lane] = maskt ? massf(tot[4], tot[5], tot[6], tot[7]) : MZ;
                mass_s[2][64 + lane] = maskt ? massf(tot[8], tot[9], tot[10], tot[11]) : MZ;
            } else {
                mass_s[0][64 + lane] = MZ;
                mass_s[1][64 + lane] = MZ;
                mass_s[2][64 + lane] = MZ;
            }
        }
    }
    __syncthreads();                               // B5

    // ---- parallel epilogue: waves 0-7 tile A, waves 8-15 tile B ----
    const int m     = w >> 3;              // 0 = tileA, 1 = tileB
    const int wl    = w & 7;
    const int col   = lane & 15;
    const int quad  = lane >> 4;
    const int mhalf = wl >> 2;             // token half within tile
    const int nBase = (wl & 3) * 128;
    unsigned short (*hsm)[88] = m ? hsB : hsA;

    // h = gelu(mass @ W1 + b1), bf16 -> hs
    {
        float q0 = mass_s[0][m * 64 + lane];
        float q1 = mass_s[1][m * 64 + lane];
        float q2 = mass_s[2][m * 64 + lane];
        unsigned short hv[8];
#pragma unroll
        for (int j = 0; j < 8; ++j) {
            int hh = wl * 8 + j;
            float pre = b1[hh];
            pre = __builtin_fmaf(q0, W1[hh], pre);
            pre = __builtin_fmaf(q1, W1[NH + hh], pre);
            pre = __builtin_fmaf(q2, W1[2 * NH + hh], pre);
            float g = 0.5f * pre * (1.0f + erff(pre * 0.70710678118654752f));
            hv[j] = f2bf(g);
        }
        *(short8*)&hsm[lane][wl * 8] = *(const short8*)hv;
    }
    __syncthreads();                               // B6

    short8 afrag[2][2];
#pragma unroll
    for (int mt = 0; mt < 2; ++mt)
#pragma unroll
        for (int ks = 0; ks < 2; ++ks)
            afrag[mt][ks] = *(const short8*)&hsm[mhalf * 32 + mt * 16 + col][ks * 32 + quad * 8];

    float4v acc[2][8];
#pragma unroll
    for (int mt = 0; mt < 2; ++mt)
#pragma unroll
        for (int nt = 0; nt < 8; ++nt)
            acc[mt][nt] = (float4v)(0.f);

#pragma unroll
    for (int nt = 0; nt < 8; ++nt) {
        const unsigned short* wp = W2t + (nBase + nt * 16 + col) * NH + quad * 8;
        short8 bf0 = *(const short8*)(wp);
        short8 bf1 = *(const short8*)(wp + 32);
        acc[0][nt] = __builtin_amdgcn_mfma_f32_16x16x32_bf16(afrag[0][0], bf0, acc[0][nt], 0, 0, 0);
        acc[1][nt] = __builtin_amdgcn_mfma_f32_16x16x32_bf16(afrag[1][0], bf0, acc[1][nt], 0, 0, 0);
        acc[0][nt] = __builtin_amdgcn_mfma_f32_16x16x32_bf16(afrag[0][1], bf1, acc[0][nt], 0, 0, 0);
        acc[1][nt] = __builtin_amdgcn_mfma_f32_16x16x32_bf16(afrag[1][1], bf1, acc[1][nt], 0, 0, 0);
    }

    const int tileBase = b * NT + (m ? tB : tA);
#pragma unroll
    for (int nt = 0; nt < 8; ++nt) {
        float bias = b2[nBase + nt * 16 + col];
#pragma unroll
        for (int mt = 0; mt < 2; ++mt) {
            int mRow = tileBase + mhalf * 32 + mt * 16 + quad * 4;
            size_t base = (size_t)mRow * ND + nBase + nt * 16 + col;
#pragma unroll
            for (int r = 0; r < 4; ++r) {
                out[base + (size_t)r * ND] = acc[mt][nt][r] + bias;
            }
        }
    }
}

extern "C" void kernel_launch(void* const* d_in, const int* in_sizes, int n_in,
                              void* d_out, int out_size, void* d_ws, size_t ws_size,
                              hipStream_t stream) {
    const float* tok  = (const float*)d_in[0];
    const int*   mask = (const int*)d_in[1];   // layout auto-detected in-kernel
    const float* W1   = (const float*)d_in[2];
    const float* b1   = (const float*)d_in[3];
    const float* W2   = (const float*)d_in[4];
    const float* b2   = (const float*)d_in[5];
    float*       out  = (float*)d_out;

    unsigned short* W2t = (unsigned short*)d_ws;                // 64 KB
    float4*         Pg  = (float4*)((char*)d_ws + 0x10000);     // 512 KB

    prep_kernel<<<dim3((ND * NH + NB * NT) / 256), dim3(256), 0, stream>>>(
        tok, mask, W2, W2t, Pg);

    dim3 gB(NT / 128, NB);
    fused_topk_mass_mlp_kernel<<<gB, dim3(1024), 0, stream>>>(
        mask, W1, b1, W2t, b2, Pg, out);
}